// Round 7
// baseline (1147.763 us; speedup 1.0000x reference)
//
#include <hip/hip_runtime.h>

// ---------------------------------------------------------------------------
// HebbianBlock: out(B,T,D) f32; chunked linear-attention style recurrence.
// Pipeline: cast->bf16 | w^T transpose | vT = Ww@rk^T (GEMM) |
//           scan(inter, W-state; dt=32, T-split P=2, GEMM1 frags direct from
//                global (dual reg-set, full-group prefetch distance), wT
//                LDS-staged, XOR-swizzle, lgkm-only barriers) |
//           corr (seg-1 state correction GEMM) | intra |
//           y = out + alpha*(inter+intra)@Wr^T (GEMM)
// ---------------------------------------------------------------------------

typedef __attribute__((ext_vector_type(8))) short short8;
typedef __attribute__((ext_vector_type(4))) short short4v;
typedef __attribute__((ext_vector_type(4))) float f32x4;

#define B_ 4
#define T_ 8192
#define D_ 1024
#define C_ 64
#define NC_ 128
#define CHS_ 64     // chunks per T-segment (NC_/2)

#define DEVI static __device__ __forceinline__

#define EXPF(x) __builtin_expf(x)
#define LOG2F(x) __builtin_log2f(x)
#define EXP2F(x) __builtin_exp2f(x)

DEVI unsigned short f2bf_u(float f) {
  unsigned int u = __float_as_uint(f);
  u += 0x7fffu + ((u >> 16) & 1u);   // round-to-nearest-even
  return (unsigned short)(u >> 16);
}
DEVI short f2bfs(float f) { return (short)f2bf_u(f); }
DEVI float bf2fs(short h) { return __uint_as_float(((unsigned int)(unsigned short)h) << 16); }

DEVI f32x4 mfma16(short8 a, short8 b, f32x4 c) {
  return __builtin_amdgcn_mfma_f32_16x16x32_bf16(a, b, c, 0, 0, 0);
}

// bare workgroup barrier: drain ONLY LDS ops (writes visible to other waves);
// global register-loads stay in flight (no vmcnt(0) drain). R3/R6 verified.
DEVI void chunk_barrier() {
  asm volatile("s_waitcnt lgkmcnt(0)" ::: "memory");
  __builtin_amdgcn_s_barrier();
}

// ---------------------------------------------------------------- cast f32->bf16
__global__ __launch_bounds__(256) void k_cast(const float* __restrict__ src,
                                              short* __restrict__ dst, int n8) {
  int i = blockIdx.x * 256 + threadIdx.x;
  if (i >= n8) return;
  const float4* s = (const float4*)src;
  float4 a = s[2 * i], b = s[2 * i + 1];
  short8 o;
  o[0] = f2bfs(a.x); o[1] = f2bfs(a.y); o[2] = f2bfs(a.z); o[3] = f2bfs(a.w);
  o[4] = f2bfs(b.x); o[5] = f2bfs(b.y); o[6] = f2bfs(b.z); o[7] = f2bfs(b.w);
  *((short8*)dst + i) = o;
}

// ---------------------------------------------------------------- w^T transpose
// wTg[b][e][t] = rk[b][t-1][e]  (pre-shifted: w_t = rk_{t-1}, t=0 -> 0)
__global__ __launch_bounds__(256) void k_transT(const short* __restrict__ rk,
                                                short* __restrict__ wTg) {
  __shared__ short ts[64][72];
  const int tid = threadIdx.x;
  const int t0 = blockIdx.x * 64, e0 = blockIdx.y * 64, b = blockIdx.z;
  const short* rk_b = rk + (size_t)b * T_ * D_;
  short* w_b = wTg + (size_t)b * D_ * T_;
  const int lr = tid >> 3, ls = tid & 7;   // 32 rows x 8 segs per pass
#pragma unroll
  for (int p = 0; p < 2; ++p) {
    int row = p * 32 + lr;                 // ts[row] holds rk[t0-1+row]
    int t = t0 - 1 + row;
    short8 v8;
    if (t >= 0) v8 = *(const short8*)(rk_b + (size_t)t * D_ + e0 + ls * 8);
    else v8 = (short8){0, 0, 0, 0, 0, 0, 0, 0};
    *(short8*)&ts[row][ls * 8] = v8;
  }
  __syncthreads();
  const int er5 = tid & 31, thi = tid >> 5;   // erow low-bits for bank spread
#pragma unroll
  for (int ep = 0; ep < 2; ++ep) {
    int erow = ep * 32 + er5;
    short8 w8;
#pragma unroll
    for (int j = 0; j < 8; ++j) w8[j] = ts[thi * 8 + j][erow];
    *(short8*)(w_b + (size_t)(e0 + erow) * T_ + t0 + thi * 8) = w8;
  }
}

// ---------------------------------------------------------------- vT = Ww @ rk^T
__global__ __launch_bounds__(256) void k_gemm_v(const short* __restrict__ Aw,
                                                const short* __restrict__ Bx,
                                                short* __restrict__ vT) {
  __shared__ short As[128][72];
  __shared__ short Bs[128][72];
  const int tid = threadIdx.x;
  const int lane = tid & 63, wv = tid >> 6;
  const int wm = (wv >> 1) * 64, wn = (wv & 1) * 64;
  const int l16 = lane & 15, q = lane >> 4;
  const int m0 = blockIdx.y * 128;
  const int n0 = blockIdx.x * 128;
  f32x4 acc[4][4];
  for (int a = 0; a < 4; ++a)
    for (int b = 0; b < 4; ++b) acc[a][b] = (f32x4){0.f, 0.f, 0.f, 0.f};
  const int lrow = tid >> 3, lseg = tid & 7;
  const short* Ap = Aw + (size_t)(m0 + lrow) * D_ + lseg * 8;
  const short* Bp = Bx + (size_t)(n0 + lrow) * D_ + lseg * 8;
  for (int kb = 0; kb < D_; kb += 64) {
#pragma unroll
    for (int p = 0; p < 4; ++p) {
      *(short8*)&As[lrow + p * 32][lseg * 8] = *(const short8*)(Ap + (size_t)(p * 32) * D_ + kb);
      *(short8*)&Bs[lrow + p * 32][lseg * 8] = *(const short8*)(Bp + (size_t)(p * 32) * D_ + kb);
    }
    __syncthreads();
#pragma unroll
    for (int ks = 0; ks < 2; ++ks) {
      short8 af[4], bfr[4];
#pragma unroll
      for (int mt = 0; mt < 4; ++mt) af[mt] = *(const short8*)&As[wm + mt * 16 + l16][ks * 32 + q * 8];
#pragma unroll
      for (int nt = 0; nt < 4; ++nt) bfr[nt] = *(const short8*)&Bs[wn + nt * 16 + l16][ks * 32 + q * 8];
#pragma unroll
      for (int mt = 0; mt < 4; ++mt)
#pragma unroll
        for (int nt = 0; nt < 4; ++nt) acc[mt][nt] = mfma16(af[mt], bfr[nt], acc[mt][nt]);
    }
    __syncthreads();
  }
  const int b = n0 >> 13;                // T_ = 8192 rows per batch
  const int tbase = (n0 & (T_ - 1)) + wn;
  short* outp = vT + (size_t)b * D_ * T_;
#pragma unroll
  for (int mt = 0; mt < 4; ++mt)
#pragma unroll
    for (int nt = 0; nt < 4; ++nt)
#pragma unroll
      for (int i = 0; i < 4; ++i) {
        int d = m0 + wm + mt * 16 + q * 4 + i;
        int t = tbase + nt * 16 + l16;
        outp[(size_t)d * T_ + t] = f2bfs(acc[mt][nt][i]);
      }
}

// ---------------------------------------------------------------- scan (inter + W state)
// grid (32 d-tiles, 4 batches, 2 T-segments), 1024 threads (16 waves).
// Per chunk: 8 slice-groups of 128 e.  GEMM1 r-fragments read DIRECTLY from
// global (L2/L3-resident) into dual alternating register sets issued one full
// group ahead; wT staged global->reg->LDS (dbuf, XOR-swz); Wb snapshot in LDS
// with c-pair reuse.  lgkm-only barriers keep global loads in flight.
// GEMM1 (inter): wave = (dsub=wv>>3, ctp=(wv>>2)&1, kr=wv&3), 2 MFMA/group
//                (c-pair shares one Wb fragment); 4-way kr reduce at epilogue.
// GEMM2 (W^T):   wave = (dh=wv>>3, et=wv&7), 2 MFMA/group into Wacc[s].
// Segment 0 writes its final state W_64 to Sg for k_corr.
__global__ __launch_bounds__(1024, 4) void k_scan(const short* __restrict__ rk,
                                                  const short* __restrict__ vT_g,
                                                  const short* __restrict__ wTg,
                                                  short* __restrict__ inter_,
                                                  short* __restrict__ Sg,
                                                  const float* __restrict__ decay_p) {
  __shared__ short wTs_[2][128][64];  // w^T rows (e) x 64 c, XOR-swz units
  __shared__ short Wb[32][1024];      // bf16 snapshot W[d][e], XOR-swz units
  __shared__ short vTs[32][72];       // v^T slice scaled by gw[c]=gamma^(63-c)
  __shared__ float red[4][64][36];    // inter partials [kr][c][d32+pad]

  const int tid = threadIdx.x;
  const int lane = tid & 63;
  const int wv = tid >> 6;                 // 0..15
  const int l16 = lane & 15, q = lane >> 4;
  const int dt = blockIdx.x, b = blockIdx.y, sg = blockIdx.z;
  const int d0 = dt * 32;
  const int tseg0 = sg * (CHS_ * 64);      // 0 or 4096
  const float gamma = 1.f / (1.f + EXPF(-decay_p[0]));
  const float lg2g = LOG2F(gamma);
  const float gC = EXP2F(64.f * lg2g);

  const short* rk_b = rk + (size_t)b * T_ * D_;
  const short* wT_b = wTg + (size_t)b * D_ * T_;
  const short* vT_b = vT_g + (size_t)b * D_ * T_;

  const int dsub = wv >> 3, ctp = (wv >> 2) & 1, kr = wv & 3;   // GEMM1 roles
  const int dh = wv >> 3, et = wv & 7;                           // GEMM2 roles
  const int l7 = l16 & 7;

  // wT staging geometry (1024 threads move 16 KB per group)
  const int wrow = tid >> 3, wunit = tid & 7;    // 128 rows x 8 units
  const short* wG = wT_b + (size_t)wrow * T_ + tseg0 + wunit * 8;
  const int wsw = (wunit ^ (wrow & 7)) * 8;

  // GEMM1 B-fragment global base: rows tseg0 + ctp*32 + {0,16} + l16,
  // cols kr*32 + q*8 (per group add ch*64 rows + s*128 cols)
  const short* afb = rk_b + (size_t)(tseg0 + ctp * 32 + l16) * D_ + kr * 32 + q * 8;

  // vTs staging: threads [512,1024) stage 32 d-rows x 64 c
  const bool vrole = (tid >= 512);
  const int vd = (tid - 512) >> 4;               // 0..31
  const int vc4 = ((tid - 512) & 15) << 2;
  const short* vptr = vT_b + (size_t)(d0 + vd) * T_ + tseg0 + vc4;
  short4v vpre;

  f32x4 Wacc[8];                     // W^T[e = s*128+et*16+q*4+i][d = dh*16+l16]
#pragma unroll
  for (int j = 0; j < 8; ++j) Wacc[j] = (f32x4){0.f, 0.f, 0.f, 0.f};
  f32x4 iacc[2];                     // inter[d=dsub*16+q*4+i][c=(2ctp+u)*16+l16]
  iacc[0] = (f32x4){0.f, 0.f, 0.f, 0.f};
  iacc[1] = (f32x4){0.f, 0.f, 0.f, 0.f};

  short8 pfW;
  auto issue_w = [&](int g2) {             // g2 = ch*8 + s
    int nch = g2 >> 3, ns = g2 & 7;
    pfW = *(const short8*)(wG + (size_t)(ns * 128) * T_ + nch * 64);
  };
  auto write_w = [&](int buf) {
    *(short8*)&wTs_[buf][wrow][wsw] = pfW;
  };
  short8 afE0, afE1, afO0, afO1;           // even/odd group fragment sets
  auto issue_afE = [&](int g2) {
    int nch = g2 >> 3, ns = g2 & 7;
    const short* p = afb + (size_t)(nch * 64) * D_ + ns * 128;
    afE0 = *(const short8*)p;
    afE1 = *(const short8*)(p + (size_t)16 * D_);
  };
  auto issue_afO = [&](int g2) {
    int nch = g2 >> 3, ns = g2 & 7;
    const short* p = afb + (size_t)(nch * 64) * D_ + ns * 128;
    afO0 = *(const short8*)p;
    afO1 = *(const short8*)(p + (size_t)16 * D_);
  };
  auto write_vTs = [&]() {
#pragma unroll
    for (int j = 0; j < 4; ++j)
      vTs[vd][vc4 + j] = f2bfs(bf2fs(vpre[j]) * EXP2F(lg2g * (float)(63 - (vc4 + j))));
  };

  // ---- prologue: stage wT group 0, af group 0 (E set), zero Wb, vTs(ch0)
  issue_w(0);
  issue_afE(0);
  if (vrole) vpre = *(const short4v*)vptr;
  write_w(0);
  if (vrole) write_vTs();
  {
    short4v z4 = (short4v){0, 0, 0, 0};
#pragma unroll
    for (int i = 0; i < 8; ++i) ((short4v*)&Wb[0][0])[tid + i * 1024] = z4;
  }
  issue_w(1);
  __syncthreads();

  short8 a2k0, a2k1;
  for (int ch = 0; ch < CHS_; ++ch) {
#pragma unroll
    for (int s = 0; s < 8; ++s) {
      const int g = ch * 8 + s;
      const int cur = s & 1;
      if (s == 0) {
        // v^T B-fragments for this chunk (vTs written at prev epilogue)
        a2k0 = *(const short8*)&vTs[dh * 16 + l16][q * 8];
        a2k1 = *(const short8*)&vTs[dh * 16 + l16][32 + q * 8];
        if (vrole) {
          int chn = (ch + 1 < CHS_) ? ch + 1 : ch;
          vpre = *(const short4v*)(vptr + chn * 64);
        }
      }
      // land wT tile g+1 (loaded during g-1), start wT loads for g+2,
      // and issue af for g+1 into the idle register set (full-group distance)
      if (g + 1 < CHS_ * 8) write_w((s + 1) & 1);
      if (g + 2 < CHS_ * 8) issue_w(g + 2);
      if (g + 1 < CHS_ * 8) {
        if ((s & 1) == 0) issue_afO(g + 1);
        else issue_afE(g + 1);
      }
      // GEMM1: inter += Wb-frag (A, d rows) x r-frag (B, c rows), c-pair reuse
      {
        short8 bfr = *(const short8*)&Wb[dsub * 16 + l16][((s * 16 + kr * 4 + q) ^ l7) * 8];
        if ((s & 1) == 0) {
          iacc[0] = mfma16(bfr, afE0, iacc[0]);
          iacc[1] = mfma16(bfr, afE1, iacc[1]);
        } else {
          iacc[0] = mfma16(bfr, afO0, iacc[0]);
          iacc[1] = mfma16(bfr, afO1, iacc[1]);
        }
      }
      // GEMM2: W^T[e][d] += wT-frag (A, e rows) x vg-frag (B, d rows)
      {
        short8 bw0 = *(const short8*)&wTs_[cur][et * 16 + l16][(q ^ l7) * 8];
        short8 bw1 = *(const short8*)&wTs_[cur][et * 16 + l16][((4 + q) ^ l7) * 8];
        Wacc[s] = mfma16(bw0, a2k0, Wacc[s]);
        Wacc[s] = mfma16(bw1, a2k1, Wacc[s]);
      }
      chunk_barrier();   // end of group: staged tile visible, reads done
    }
    // ---- chunk epilogue ----
    // inter partial dump (c-pair) + reset
    *(f32x4*)&red[kr][(ctp * 2) * 16 + l16][dsub * 16 + q * 4] = iacc[0];
    *(f32x4*)&red[kr][(ctp * 2 + 1) * 16 + l16][dsub * 16 + q * 4] = iacc[1];
    iacc[0] = (f32x4){0.f, 0.f, 0.f, 0.f};
    iacc[1] = (f32x4){0.f, 0.f, 0.f, 0.f};
    // W snapshot (pre-decay) -> Wb[d][e] (swizzled); then decay state
    {
      const int row_d = dh * 16 + l16;
#pragma unroll
      for (int s2 = 0; s2 < 8; ++s2) {
        short4v w4;
#pragma unroll
        for (int i = 0; i < 4; ++i) w4[i] = f2bfs(Wacc[s2][i]);
        int e_base = s2 * 128 + et * 16 + q * 4;
        int unit = e_base >> 3;
        *(short4v*)&Wb[row_d][((unit ^ l7) << 3) + (e_base & 7)] = w4;
        if (sg == 0 && ch == CHS_ - 1)   // segment-0 final state -> Sg
          *(short4v*)(Sg + ((size_t)b * D_ + d0 + row_d) * D_ + e_base) = w4;
#pragma unroll
        for (int i = 0; i < 4; ++i) Wacc[s2][i] *= gC;
      }
    }
    if (vrole && ch + 1 < CHS_) write_vTs();
    chunk_barrier();   // Wb/red/vTs ready
    // reduce 4 kr partials, scale by gamma^c, store bf16 (waves 0-3)
    if (tid < 256) {
      int c = tid >> 2, dq = tid & 3;
      f32x4 s0 = *(const f32x4*)&red[0][c][dq * 8];
      f32x4 s1 = *(const f32x4*)&red[0][c][dq * 8 + 4];
#pragma unroll
      for (int p = 1; p < 4; ++p) {
        s0 += *(const f32x4*)&red[p][c][dq * 8];
        s1 += *(const f32x4*)&red[p][c][dq * 8 + 4];
      }
      float sc = EXP2F(lg2g * (float)c);
      short8 o;
#pragma unroll
      for (int i = 0; i < 4; ++i) { o[i] = f2bfs(s0[i] * sc); o[4 + i] = f2bfs(s1[i] * sc); }
      *(short8*)(inter_ + (size_t)b * T_ * D_ +
                 (size_t)(tseg0 + ch * 64 + c) * D_ + d0 + dq * 8) = o;
    }
  }
}

// ---------------------------------------------------------------- seg-1 correction
// inter[b][4096+lt][d] += gamma^lt * sum_e rk[b][4096+lt][e] * Sg[b][d][e],
// for lt in [0,2048) (gamma^2048 ~ 1e-9: below bf16 resolution -> skipped).
__global__ __launch_bounds__(256) void k_corr(const short* __restrict__ rk,
                                              const short* __restrict__ Sg,
                                              short* __restrict__ inter_,
                                              const float* __restrict__ decay_p) {
  __shared__ short As[128][72];
  __shared__ short Bs[128][72];
  const int tid = threadIdx.x;
  const int lane = tid & 63, wv = tid >> 6;
  const int wm = (wv >> 1) * 64, wn = (wv & 1) * 64;
  const int l16 = lane & 15, q = lane >> 4;
  const int m0 = blockIdx.x * 128;         // lt tile
  const int n0 = blockIdx.y * 128;         // d tile
  const int b = blockIdx.z;
  const float gamma = 1.f / (1.f + EXPF(-decay_p[0]));
  const float lg2g = LOG2F(gamma);
  const short* Ab = rk + (size_t)b * T_ * D_ + (size_t)(4096 + m0) * D_;
  const short* Bb = Sg + (size_t)b * D_ * D_ + (size_t)n0 * D_;
  f32x4 acc[4][4];
  for (int a = 0; a < 4; ++a)
    for (int c = 0; c < 4; ++c) acc[a][c] = (f32x4){0.f, 0.f, 0.f, 0.f};
  const int lrow = tid >> 3, lseg = tid & 7;
  for (int kb = 0; kb < D_; kb += 64) {
#pragma unroll
    for (int p = 0; p < 4; ++p) {
      *(short8*)&As[lrow + p * 32][lseg * 8] =
          *(const short8*)(Ab + (size_t)(lrow + p * 32) * D_ + kb + lseg * 8);
      *(short8*)&Bs[lrow + p * 32][lseg * 8] =
          *(const short8*)(Bb + (size_t)(lrow + p * 32) * D_ + kb + lseg * 8);
    }
    __syncthreads();
#pragma unroll
    for (int ks = 0; ks < 2; ++ks) {
      short8 af[4], bfr[4];
#pragma unroll
      for (int mt = 0; mt < 4; ++mt) af[mt] = *(const short8*)&As[wm + mt * 16 + l16][ks * 32 + q * 8];
#pragma unroll
      for (int nt = 0; nt < 4; ++nt) bfr[nt] = *(const short8*)&Bs[wn + nt * 16 + l16][ks * 32 + q * 8];
#pragma unroll
      for (int mt = 0; mt < 4; ++mt)
#pragma unroll
        for (int nt = 0; nt < 4; ++nt) acc[mt][nt] = mfma16(af[mt], bfr[nt], acc[mt][nt]);
    }
    __syncthreads();
  }
#pragma unroll
  for (int mt = 0; mt < 4; ++mt)
#pragma unroll
    for (int nt = 0; nt < 4; ++nt)
#pragma unroll
      for (int i = 0; i < 4; ++i) {
        int lt = m0 + wm + mt * 16 + q * 4 + i;
        int d = n0 + wn + nt * 16 + l16;
        size_t idx = (size_t)b * T_ * D_ + (size_t)(4096 + lt) * D_ + d;
        float cur = bf2fs(inter_[idx]);
        inter_[idx] = f2bfs(cur + acc[mt][nt][i] * EXP2F(lg2g * (float)lt));
      }
}

// ---------------------------------------------------------------- intra chunk
__global__ __launch_bounds__(256) void k_intra(const short* __restrict__ rk,
                                               const short* __restrict__ vT_g,
                                               short* __restrict__ intra_,
                                               const float* __restrict__ decay_p) {
  __shared__ short rs[65][264];
  __shared__ short P[64][72];
  __shared__ short vs[256][72];
  const int tid = threadIdx.x;
  const int lane = tid & 63, wv = tid >> 6;
  const int l16 = lane & 15, q = lane >> 4;
  const int ch = blockIdx.x, b = blockIdx.y;
  const int t0 = ch << 6;
  const float gamma = 1.f / (1.f + EXPF(-decay_p[0]));
  const float lg2g = LOG2F(gamma);
  const short* rk_b = rk + (size_t)b * T_ * D_;
  f32x4 Sacc[4];
#pragma unroll
  for (int j = 0; j < 4; ++j) Sacc[j] = (f32x4){0.f, 0.f, 0.f, 0.f};

  for (int s = 0; s < 4; ++s) {
    const int e0 = s << 8;
#pragma unroll
    for (int p = 0; p < 9; ++p) {
      int idx = p * 256 + tid;
      if (idx < 2080) {
        int row = idx >> 5, seg = idx & 31;
        int t = t0 - 1 + row;
        short8 v8;
        if (t >= 0) v8 = *(const short8*)(rk_b + (size_t)t * D_ + e0 + seg * 8);
        else v8 = (short8){0, 0, 0, 0, 0, 0, 0, 0};
        *(short8*)&rs[row][seg * 8] = v8;
      }
    }
    __syncthreads();
#pragma unroll
    for (int ks = 0; ks < 8; ++ks) {
      short8 af = *(const short8*)&rs[wv * 16 + l16 + 1][ks * 32 + q * 8];   // r rows
#pragma unroll
      for (int nt = 0; nt < 4; ++nt) {
        short8 bfr = *(const short8*)&rs[nt * 16 + l16][ks * 32 + q * 8];    // w rows
        Sacc[nt] = mfma16(af, bfr, Sacc[nt]);
      }
    }
    __syncthreads();
  }
  // mask: P[c][c'] = S * gamma^(c-1-c') for c>c', else 0
#pragma unroll
  for (int nt = 0; nt < 4; ++nt)
#pragma unroll
    for (int i = 0; i < 4; ++i) {
      int c = wv * 16 + q * 4 + i;
      int cp = nt * 16 + l16;
      float m = (c > cp) ? EXP2F(lg2g * (float)(c - 1 - cp)) : 0.f;
      P[c][cp] = f2bfs(Sacc[nt][i] * m);
    }
  __syncthreads();
  const short* vsrc = vT_g + (size_t)b * D_ * T_ + (size_t)tid * T_ + t0;
  size_t base = (size_t)b * T_ * D_;
  for (int p = 0; p < 4; ++p) {
    const short* sp = vsrc + (size_t)(p * 256) * T_;
#pragma unroll
    for (int seg = 0; seg < 8; ++seg)
      *(short8*)&vs[tid][seg * 8] = *(const short8*)(sp + seg * 8);
    __syncthreads();
    f32x4 acc[4][4];
#pragma unroll
    for (int a = 0; a < 4; ++a)
#pragma unroll
      for (int bb = 0; bb < 4; ++bb) acc[a][bb] = (f32x4){0.f, 0.f, 0.f, 0.f};
#pragma unroll
    for (int ks2 = 0; ks2 < 2; ++ks2) {
      short8 af[4];
#pragma unroll
      for (int mt = 0; mt < 4; ++mt) af[mt] = *(const short8*)&P[mt * 16 + l16][ks2 * 32 + q * 8];
#pragma unroll
      for (int nt = 0; nt < 4; ++nt) {
        short8 bfr = *(const short8*)&vs[wv * 64 + nt * 16 + l16][ks2 * 32 + q * 8];
#pragma unroll
        for (int mt = 0; mt < 4; ++mt) acc[mt][nt] = mfma16(af[mt], bfr, acc[mt][nt]);
      }
    }
#pragma unroll
    for (int mt = 0; mt < 4; ++mt)
#pragma unroll
      for (int nt = 0; nt < 4; ++nt)
#pragma unroll
        for (int i = 0; i < 4; ++i) {
          int c = mt * 16 + q * 4 + i;
          int d = p * 256 + wv * 64 + nt * 16 + l16;
          intra_[base + (size_t)(t0 + c) * D_ + d] = f2bfs(acc[mt][nt][i]);
        }
    __syncthreads();
  }
}

// ---------------------------------------------------------------- final GEMM
__global__ __launch_bounds__(256) void k_gemm_final(const short* __restrict__ inter_,
                                                    const short* __restrict__ intra_,
                                                    const short* __restrict__ Wr,
                                                    const float* __restrict__ xin,
                                                    float* __restrict__ y,
                                                    const float* __restrict__ la_p) {
  __shared__ short As[128][72];
  __shared__ short Bs[128][72];
  const float alpha = EXPF(la_p[0]);
  const int tid = threadIdx.x;
  const int lane = tid & 63, wv = tid >> 6;
  const int wm = (wv >> 1) * 64, wn = (wv & 1) * 64;
  const int l16 = lane & 15, q = lane >> 4;
  const int m0 = blockIdx.x * 128;
  const int n0 = blockIdx.y * 128;
  f32x4 acc[4][4];
  for (int a = 0; a < 4; ++a)
    for (int b = 0; b < 4; ++b) acc[a][b] = (f32x4){0.f, 0.f, 0.f, 0.f};
  const int lrow = tid >> 3, lseg = tid & 7;
  for (int kb = 0; kb < D_; kb += 64) {
#pragma unroll
    for (int p = 0; p < 4; ++p) {
      size_t aoff = (size_t)(m0 + lrow + p * 32) * D_ + kb + lseg * 8;
      short8 xa = *(const short8*)(inter_ + aoff);
      short8 xb = *(const short8*)(intra_ + aoff);
      short8 xs;
#pragma unroll
      for (int j = 0; j < 8; ++j) xs[j] = f2bfs(bf2fs(xa[j]) + bf2fs(xb[j]));
      *(short8*)&As[lrow + p * 32][lseg * 8] = xs;
      *(short8*)&Bs[lrow + p * 32][lseg * 8] =
          *(const short8*)(Wr + (size_t)(n0 + lrow + p * 32) * D_ + kb + lseg * 8);
    }
    __syncthreads();
#pragma unroll
    for (int ks = 0; ks < 2; ++ks) {
      short8 af[4], bfr[4];
#pragma unroll
      for (int mt = 0; mt < 4; ++mt) af[mt] = *(const short8*)&As[wm + mt * 16 + l16][ks * 32 + q * 8];
#pragma unroll
      for (int nt = 0; nt < 4; ++nt) bfr[nt] = *(const short8*)&Bs[wn + nt * 16 + l16][ks * 32 + q * 8];
#pragma unroll
      for (int mt = 0; mt < 4; ++mt)
#pragma unroll
        for (int nt = 0; nt < 4; ++nt) acc[mt][nt] = mfma16(af[mt], bfr[nt], acc[mt][nt]);
    }
    __syncthreads();
  }
#pragma unroll
  for (int mt = 0; mt < 4; ++mt)
#pragma unroll
    for (int nt = 0; nt < 4; ++nt)
#pragma unroll
      for (int i = 0; i < 4; ++i) {
        int t = m0 + wm + mt * 16 + q * 4 + i;
        int d = n0 + wn + nt * 16 + l16;
        size_t idx = (size_t)t * D_ + d;
        y[idx] = xin[idx] + alpha * acc[mt][nt][i];
      }
}

// ---------------------------------------------------------------- launch
extern "C" void kernel_launch(void* const* d_in, const int* in_sizes, int n_in,
                              void* d_out, int out_size, void* d_ws, size_t ws_size,
                              hipStream_t stream) {
  const float* x = (const float*)d_in[0];
  const float* Ww = (const float*)d_in[1];
  const float* Wr = (const float*)d_in[2];
  const float* decay = (const float*)d_in[3];
  const float* log_alpha = (const float*)d_in[4];
  float* y = (float*)d_out;

  short* ws = (short*)d_ws;
  const size_t NTD = (size_t)B_ * T_ * D_;   // 33,554,432
  short* rk_bf = ws;
  short* vT_bf = rk_bf + NTD;
  short* inter_b = vT_bf + NTD;
  short* intra_b = inter_b + NTD;
  short* Ww_bf = intra_b + NTD;
  short* Wr_bf = Ww_bf + (size_t)D_ * D_;
  short* Sg = Wr_bf + (size_t)D_ * D_;       // B x D x D bf16 (8 MB)
  // wTg aliases intra_b: only live between k_transT and k_scan; k_intra
  // overwrites it afterwards. total ws: 4*NTD + (2+B)*D*D shorts ~ 281 MB.
  short* wTg = intra_b;

  k_cast<<<(int)(NTD / 8 / 256), 256, 0, stream>>>(x, rk_bf, (int)(NTD / 8));
  k_cast<<<512, 256, 0, stream>>>(Ww, Ww_bf, (D_ * D_) / 8);
  k_cast<<<512, 256, 0, stream>>>(Wr, Wr_bf, (D_ * D_) / 8);
  k_transT<<<dim3(T_ / 64, D_ / 64, B_), 256, 0, stream>>>(rk_bf, wTg);
  k_gemm_v<<<dim3(256, 8), 256, 0, stream>>>(Ww_bf, rk_bf, vT_bf);
  k_scan<<<dim3(32, 4, 2), 1024, 0, stream>>>(rk_bf, vT_bf, wTg, inter_b, Sg, decay);
  k_corr<<<dim3(16, 8, 4), 256, 0, stream>>>(rk_bf, Sg, inter_b, decay);
  k_intra<<<dim3(128, 4), 256, 0, stream>>>(rk_bf, vT_bf, intra_b, decay);
  k_gemm_final<<<dim3(256, 8), 256, 0, stream>>>(inter_b, intra_b, Wr_bf, x, y, log_alpha);
}